// Round 2
// baseline (114.350 us; speedup 1.0000x reference)
//
#include <hip/hip_runtime.h>
#include <math.h>

#define SA 20        // alphabet
#define KDIM 2
#define MDIM 2
#define BDIM 512
#define LDIM 512
#define NRATES 512
#define PPB 4        // (m,b) pairs per block (one per wave) in compute kernel
#define THREADS 256
#define NCH (LDIM * KDIM * SA / 4)   // 5120 float4 chunks per pair
#define PFLOATS (KDIM * SA * SA)     // 800 floats of P per pair
#define WS_NEEDED ((size_t)MDIM * BDIM * PFLOATS * sizeof(float))  // 3,276,800 B

// ---- gather kernel geometry: one block per (pair, half of L) ----
#define G_BLOCKS (MDIM * BDIM * 2)   // 2048 -> 8 blocks/CU -> full occupancy
#define HALF_L (LDIM / 2)            // 256
#define CH_PER_BLOCK (NCH / 2)       // 2560 float4 chunks per block

__device__ __forceinline__ float softplusf(float x) {
    return fmaxf(x, 0.0f) + log1pf(expf(-fabsf(x)));
}

// C(row-per-lane regs) = A(row-per-lane regs) * B (LDS, 20x20 row-major, 16B-aligned)
// Same-address float4 LDS reads broadcast: conflict-free.
__device__ __forceinline__ void mmB(float* C, const float* A, const float* Bl) {
    #pragma unroll
    for (int j = 0; j < SA; ++j) C[j] = 0.0f;
    #pragma unroll
    for (int t = 0; t < SA; ++t) {
        const float a = A[t];
        const float4* row = reinterpret_cast<const float4*>(Bl + t * SA);
        #pragma unroll
        for (int q = 0; q < 5; ++q) {
            float4 b = row[q];
            C[4*q+0] = fmaf(a, b.x, C[4*q+0]);
            C[4*q+1] = fmaf(a, b.y, C[4*q+1]);
            C[4*q+2] = fmaf(a, b.z, C[4*q+2]);
            C[4*q+3] = fmaf(a, b.w, C[4*q+3]);
        }
    }
}

__device__ __forceinline__ void stageRow(float* dst, const float* T, int row, bool act) {
    if (act) {
        float4* d4 = reinterpret_cast<float4*>(dst + row * SA);
        #pragma unroll
        for (int q = 0; q < 5; ++q)
            d4[q] = make_float4(T[4*q+0], T[4*q+1], T[4*q+2], T[4*q+3]);
    }
}

// ============================================================================
// Kernel 1: expm compute only. One wave per (m,b) pair (lanes: half=k, row).
// Writes final P rows register->global workspace. ~3.2 MB total.
// ============================================================================
__global__ __launch_bounds__(THREADS) void compute_P_kernel(
    const int*   __restrict__ rateIdx,
    const float* __restrict__ tauk,
    const float* __restrict__ Ek,
    const float* __restrict__ eqk,
    float*       __restrict__ Pws)
{
    __shared__ float sP[PPB * KDIM * SA * SA];   // matmul B-operand staging

    const int tid  = threadIdx.x;
    const int w    = tid >> 6;          // wave id == local pair id
    const int lane = tid & 63;
    const int mb   = blockIdx.x * PPB + w;   // global pair in [0, 1024)
    const int mm   = mb >> 9;                // BDIM = 512

    const int  half = lane >> 5;        // which k
    const int  row  = lane & 31;
    const bool act  = row < SA;
    const int  mk   = mm * KDIM + half;
    float* stage = sP + (w * KDIM + half) * SA * SA;

    // ---- fused qmat: p = softmax(eqk), R = softplus(sym(Ek)) off-diag, normalize ----
    float e = act ? eqk[mk * SA + row] : -INFINITY;
    float mx = e;
    #pragma unroll
    for (int off = 16; off; off >>= 1) mx = fmaxf(mx, __shfl_xor(mx, off, 32));
    float ex = act ? expf(e - mx) : 0.0f;
    float sm = ex;
    #pragma unroll
    for (int off = 16; off; off >>= 1) sm += __shfl_xor(sm, off, 32);
    float p_i = ex / sm;

    const int r0 = act ? row : 0;
    float A[SA];
    float dg = 0.0f;
    #pragma unroll
    for (int j = 0; j < SA; ++j) {
        float pj = __shfl(p_i, j, 32);
        float e1 = Ek[(mk * SA + r0) * SA + j];
        float e2 = Ek[(mk * SA + j) * SA + r0];
        float r  = (j == row) ? 0.0f : softplusf(0.5f * (e1 + e2));
        float q  = r * pj;
        A[j] = q;
        dg  += q;
    }
    float t_ = act ? p_i * dg : 0.0f;
    #pragma unroll
    for (int off = 16; off; off >>= 1) t_ += __shfl_xor(t_, off, 32);
    const float inv = 1.0f / fmaxf(t_, 1e-16f);

    const float tau = softplusf(tauk[mm * NRATES + rateIdx[mb]]);
    const float sc  = tau * inv;
    #pragma unroll
    for (int j = 0; j < SA; ++j)
        A[j] = act ? ((j == row) ? -dg * sc : A[j] * sc) : 0.0f;

    // ---- scaling: s = ceil(log2(||A||inf / theta)), theta = 1.0 ----
    float rn = 0.0f;
    #pragma unroll
    for (int j = 0; j < SA; ++j) rn += fabsf(A[j]);
    #pragma unroll
    for (int off = 16; off; off >>= 1) rn = fmaxf(rn, __shfl_xor(rn, off, 32));
    int s = 0;
    if (rn > 1.0f) s = (int)ceilf(log2f(rn));
    if (s < 0) s = 0;
    if (s > 30) s = 30;
    const float scale = exp2f((float)(-s));
    #pragma unroll
    for (int j = 0; j < SA; ++j) A[j] *= scale;
    const int smax = max(s, __shfl_xor(s, 32, 64));

    // ---- degree-6 Paterson-Stockmeyer Taylor: 3 matmuls ----
    float A2[SA], A3[SA], T[SA];
    stageRow(stage, A, row, act);
    mmB(A2, A, stage);
    mmB(A3, A2, stage);
    #pragma unroll
    for (int j = 0; j < SA; ++j) {
        float id = (j == row) ? 1.0f : 0.0f;
        T[j] = (1.0f/6.0f)*id + (1.0f/24.0f)*A[j] + (1.0f/120.0f)*A2[j] + (1.0f/720.0f)*A3[j];
    }
    stageRow(stage, T, row, act);      // stage B1
    {
        float P1[SA];
        mmB(P1, A3, stage);
        #pragma unroll
        for (int j = 0; j < SA; ++j) {
            float id = (j == row) ? 1.0f : 0.0f;
            T[j] = P1[j] + id + A[j] + 0.5f * A2[j];
        }
    }
    // ---- squarings (typically 0) ----
    for (int it = 0; it < smax; ++it) {
        stageRow(stage, T, row, act);
        float Tn[SA];
        mmB(Tn, T, stage);
        const bool doit = it < s;
        #pragma unroll
        for (int j = 0; j < SA; ++j) T[j] = doit ? Tn[j] : T[j];
    }

    // ---- write final P row straight from registers to workspace ----
    // float offset = ((mb*2+half)*20+row)*20 -> multiple of 20 floats = 80 B -> 16B aligned
    if (act) {
        float4* d4 = reinterpret_cast<float4*>(
            Pws + ((size_t)(mb * KDIM + half) * SA + row) * SA);
        #pragma unroll
        for (int q = 0; q < 5; ++q)
            d4[q] = make_float4(T[4*q+0], T[4*q+1], T[4*q+2], T[4*q+3]);
    }
}

// ============================================================================
// Kernel 2: lean streaming gather. 2048 blocks (8/CU, full occupancy, tiny
// VGPR footprint). Block = one (pair, half of L). LDS: 3.2 KB P + 1 KB seq.
// out[mb,l,kk,:] = P[mb,kk,seq[l],:], written as coalesced float4.
// ============================================================================
__global__ __launch_bounds__(256, 8) void gather_out_kernel(
    const int*   __restrict__ seqg,
    const float* __restrict__ Pws,
    float*       __restrict__ out)
{
    __shared__ float4 sP4[PFLOATS / 4];   // 200 float4 = 3.2 KB
    __shared__ int    sSeq[HALF_L];       // 1 KB

    const int tid  = threadIdx.x;
    const int bid  = blockIdx.x;
    const int mb   = bid >> 1;
    const int half = bid & 1;

    if (tid < PFLOATS / 4)
        sP4[tid] = reinterpret_cast<const float4*>(Pws)[mb * (PFLOATS / 4) + tid];
    sSeq[tid] = seqg[mb * LDIM + half * HALF_L + tid];
    __syncthreads();

    float4* o4 = reinterpret_cast<float4*>(out)
               + (size_t)mb * NCH + (size_t)half * CH_PER_BLOCK;

    #pragma unroll
    for (int i = 0; i < CH_PER_BLOCK / 256; ++i) {    // 10 iterations
        const int lf = tid + i * 256;                 // [0, 2560)
        const int l  = (lf * 6554) >> 16;             // lf/10  (exact for lf < 16384)
        const int ch = lf - l * 10;
        const int kk = (ch >= 5) ? 1 : 0;
        const int c4 = ch - kk * 5;
        const int sq = sSeq[l];
        o4[lf] = sP4[(kk * SA + sq) * 5 + c4];
    }
}

// ============================================================================
// Fallback: original fused single-kernel path (used only if ws is too small).
// ============================================================================
__global__ __launch_bounds__(THREADS) void ancprobs_fused_kernel(
    const int*   __restrict__ seqg,
    const int*   __restrict__ rateIdx,
    const float* __restrict__ tauk,
    const float* __restrict__ Ek,
    const float* __restrict__ eqk,
    float*       __restrict__ out)
{
    __shared__ float sP[PPB * KDIM * SA * SA];
    __shared__ int   sSeq[PPB * LDIM];

    const int tid  = threadIdx.x;
    const int w    = tid >> 6;
    const int lane = tid & 63;
    const int mb   = blockIdx.x * PPB + w;
    const int mm   = mb >> 9;

    {
        const int4* sq = reinterpret_cast<const int4*>(seqg + (size_t)mb * LDIM);
        int4* dst = reinterpret_cast<int4*>(sSeq + w * LDIM);
        dst[lane]      = sq[lane];
        dst[lane + 64] = sq[lane + 64];
    }

    const int  half = lane >> 5;
    const int  row  = lane & 31;
    const bool act  = row < SA;
    const int  mk   = mm * KDIM + half;
    float* stage = sP + (w * KDIM + half) * SA * SA;

    float e = act ? eqk[mk * SA + row] : -INFINITY;
    float mx = e;
    #pragma unroll
    for (int off = 16; off; off >>= 1) mx = fmaxf(mx, __shfl_xor(mx, off, 32));
    float ex = act ? expf(e - mx) : 0.0f;
    float sm = ex;
    #pragma unroll
    for (int off = 16; off; off >>= 1) sm += __shfl_xor(sm, off, 32);
    float p_i = ex / sm;

    const int r0 = act ? row : 0;
    float A[SA];
    float dg = 0.0f;
    #pragma unroll
    for (int j = 0; j < SA; ++j) {
        float pj = __shfl(p_i, j, 32);
        float e1 = Ek[(mk * SA + r0) * SA + j];
        float e2 = Ek[(mk * SA + j) * SA + r0];
        float r  = (j == row) ? 0.0f : softplusf(0.5f * (e1 + e2));
        float q  = r * pj;
        A[j] = q;
        dg  += q;
    }
    float t_ = act ? p_i * dg : 0.0f;
    #pragma unroll
    for (int off = 16; off; off >>= 1) t_ += __shfl_xor(t_, off, 32);
    const float inv = 1.0f / fmaxf(t_, 1e-16f);

    const float tau = softplusf(tauk[mm * NRATES + rateIdx[mb]]);
    const float sc  = tau * inv;
    #pragma unroll
    for (int j = 0; j < SA; ++j)
        A[j] = act ? ((j == row) ? -dg * sc : A[j] * sc) : 0.0f;

    float rn = 0.0f;
    #pragma unroll
    for (int j = 0; j < SA; ++j) rn += fabsf(A[j]);
    #pragma unroll
    for (int off = 16; off; off >>= 1) rn = fmaxf(rn, __shfl_xor(rn, off, 32));
    int s = 0;
    if (rn > 1.0f) s = (int)ceilf(log2f(rn));
    if (s < 0) s = 0;
    if (s > 30) s = 30;
    const float scale = exp2f((float)(-s));
    #pragma unroll
    for (int j = 0; j < SA; ++j) A[j] *= scale;
    const int smax = max(s, __shfl_xor(s, 32, 64));

    float A2[SA], A3[SA], T[SA];
    stageRow(stage, A, row, act);
    mmB(A2, A, stage);
    mmB(A3, A2, stage);
    #pragma unroll
    for (int j = 0; j < SA; ++j) {
        float id = (j == row) ? 1.0f : 0.0f;
        T[j] = (1.0f/6.0f)*id + (1.0f/24.0f)*A[j] + (1.0f/120.0f)*A2[j] + (1.0f/720.0f)*A3[j];
    }
    stageRow(stage, T, row, act);
    {
        float P1[SA];
        mmB(P1, A3, stage);
        #pragma unroll
        for (int j = 0; j < SA; ++j) {
            float id = (j == row) ? 1.0f : 0.0f;
            T[j] = P1[j] + id + A[j] + 0.5f * A2[j];
        }
    }
    for (int it = 0; it < smax; ++it) {
        stageRow(stage, T, row, act);
        float Tn[SA];
        mmB(Tn, T, stage);
        const bool doit = it < s;
        #pragma unroll
        for (int j = 0; j < SA; ++j) T[j] = doit ? Tn[j] : T[j];
    }
    stageRow(stage, T, row, act);

    __syncthreads();

    const float4* pv = reinterpret_cast<const float4*>(sP);
    #pragma unroll 1
    for (int pr = 0; pr < PPB; ++pr) {
        float4* o4 = reinterpret_cast<float4*>(out) + (size_t)(blockIdx.x * PPB + pr) * NCH;
        const int* sq = sSeq + pr * LDIM;
        for (int f = tid; f < NCH; f += THREADS) {
            int l  = f / 10;
            int ch = f - l * 10;
            int kk = (ch >= 5) ? 1 : 0;
            int c4 = ch - kk * 5;
            o4[f] = pv[((pr * KDIM + kk) * SA + sq[l]) * 5 + c4];
        }
    }
}

extern "C" void kernel_launch(void* const* d_in, const int* in_sizes, int n_in,
                              void* d_out, int out_size, void* d_ws, size_t ws_size,
                              hipStream_t stream) {
    const int*   seq  = (const int*)d_in[0];
    const int*   ridx = (const int*)d_in[1];
    const float* tauk = (const float*)d_in[2];
    const float* Ek   = (const float*)d_in[3];
    const float* eqk  = (const float*)d_in[4];
    float* out = (float*)d_out;

    if (d_ws != nullptr && ws_size >= WS_NEEDED) {
        float* Pws = (float*)d_ws;
        compute_P_kernel<<<(MDIM * BDIM) / PPB, THREADS, 0, stream>>>(
            ridx, tauk, Ek, eqk, Pws);
        gather_out_kernel<<<G_BLOCKS, 256, 0, stream>>>(seq, Pws, out);
    } else {
        // Fallback: verified fused path (no workspace dependency)
        ancprobs_fused_kernel<<<(MDIM * BDIM) / PPB, THREADS, 0, stream>>>(
            seq, ridx, tauk, Ek, eqk, out);
    }
}

// Round 3
// 108.983 us; speedup vs baseline: 1.0492x; 1.0492x over previous
//
#include <hip/hip_runtime.h>
#include <math.h>

#define SA 20        // alphabet
#define KDIM 2
#define MDIM 2
#define BDIM 512
#define LDIM 512
#define NRATES 512
#define PPB 4        // (m,b) pairs per block, one per wave
#define THREADS 256
#define NCH (LDIM * KDIM * SA / 4)   // 5120 float4 chunks per pair

__device__ __forceinline__ float softplusf(float x) {
    return fmaxf(x, 0.0f) + log1pf(expf(-fabsf(x)));
}

// C(row-per-lane regs) = A(row-per-lane regs) * B (LDS, 20x20 row-major, 16B-aligned)
// Same-address float4 LDS reads broadcast: conflict-free. Wave-private slot:
// no __syncthreads needed (in-wave lgkmcnt ordering).
__device__ __forceinline__ void mmB(float* C, const float* A, const float* Bl) {
    #pragma unroll
    for (int j = 0; j < SA; ++j) C[j] = 0.0f;
    #pragma unroll
    for (int t = 0; t < SA; ++t) {
        const float a = A[t];
        const float4* row = reinterpret_cast<const float4*>(Bl + t * SA);
        #pragma unroll
        for (int q = 0; q < 5; ++q) {
            float4 b = row[q];
            C[4*q+0] = fmaf(a, b.x, C[4*q+0]);
            C[4*q+1] = fmaf(a, b.y, C[4*q+1]);
            C[4*q+2] = fmaf(a, b.z, C[4*q+2]);
            C[4*q+3] = fmaf(a, b.w, C[4*q+3]);
        }
    }
}

__device__ __forceinline__ void stageRow(float* dst, const float* T, int row, bool act) {
    if (act) {
        float4* d4 = reinterpret_cast<float4*>(dst + row * SA);
        #pragma unroll
        for (int q = 0; q < 5; ++q)
            d4[q] = make_float4(T[4*q+0], T[4*q+1], T[4*q+2], T[4*q+3]);
    }
}

// ============================================================================
// Fused kernel, barrier-free: each wave owns one (m,b) pair end-to-end.
//   lanes: half = lane>>5 selects k; row = lane&31 (rows 0..19 active).
//   expm into wave-private LDS slot, then the wave streams its own 80 KB of
//   output immediately — no __syncthreads, waves stagger so the first wave's
//   store drain overlaps later waves' expm.
// ============================================================================
__global__ __launch_bounds__(THREADS) void ancprobs_fused_kernel(
    const int*   __restrict__ seqg,
    const int*   __restrict__ rateIdx,
    const float* __restrict__ tauk,
    const float* __restrict__ Ek,
    const float* __restrict__ eqk,
    float*       __restrict__ out)
{
    __shared__ float sP[PPB * KDIM * SA * SA];   // 4 waves x 800 floats = 12.8 KB
    __shared__ int   sSeq[PPB * LDIM];           // 8 KB

    const int tid  = threadIdx.x;
    const int w    = tid >> 6;          // wave id == local pair id
    const int lane = tid & 63;
    const int mb   = blockIdx.x * PPB + w;   // global pair in [0, 1024)
    const int mm   = mb >> 9;                // BDIM = 512

    // ---- stage this wave's sequence early (512 ints = 2 int4 per lane) ----
    {
        const int4* sq = reinterpret_cast<const int4*>(seqg + (size_t)mb * LDIM);
        int4* dst = reinterpret_cast<int4*>(sSeq + w * LDIM);
        dst[lane]      = sq[lane];
        dst[lane + 64] = sq[lane + 64];
    }

    const int  half = lane >> 5;        // which k
    const int  row  = lane & 31;
    const bool act  = row < SA;
    const int  mk   = mm * KDIM + half;
    float* stage = sP + (w * KDIM + half) * SA * SA;  // this half's 400-float slot

    // ---- fused qmat: p = softmax(eqk), R = softplus(sym(Ek)) off-diag, normalize ----
    float e = act ? eqk[mk * SA + row] : -INFINITY;
    float mx = e;
    #pragma unroll
    for (int off = 16; off; off >>= 1) mx = fmaxf(mx, __shfl_xor(mx, off, 32));
    float ex = act ? expf(e - mx) : 0.0f;
    float sm = ex;
    #pragma unroll
    for (int off = 16; off; off >>= 1) sm += __shfl_xor(sm, off, 32);
    float p_i = ex / sm;

    const int r0 = act ? row : 0;
    float A[SA];
    float dg = 0.0f;
    #pragma unroll
    for (int j = 0; j < SA; ++j) {
        float pj = __shfl(p_i, j, 32);
        float e1 = Ek[(mk * SA + r0) * SA + j];
        float e2 = Ek[(mk * SA + j) * SA + r0];
        float r  = (j == row) ? 0.0f : softplusf(0.5f * (e1 + e2));
        float q  = r * pj;
        A[j] = q;
        dg  += q;
    }
    float t_ = act ? p_i * dg : 0.0f;
    #pragma unroll
    for (int off = 16; off; off >>= 1) t_ += __shfl_xor(t_, off, 32);
    const float inv = 1.0f / fmaxf(t_, 1e-16f);

    const float tau = softplusf(tauk[mm * NRATES + rateIdx[mb]]);
    const float sc  = tau * inv;
    #pragma unroll
    for (int j = 0; j < SA; ++j)
        A[j] = act ? ((j == row) ? -dg * sc : A[j] * sc) : 0.0f;

    // ---- scaling: s = ceil(log2(||A||inf / theta)), theta = 1.0 ----
    float rn = 0.0f;
    #pragma unroll
    for (int j = 0; j < SA; ++j) rn += fabsf(A[j]);
    #pragma unroll
    for (int off = 16; off; off >>= 1) rn = fmaxf(rn, __shfl_xor(rn, off, 32));
    int s = 0;
    if (rn > 1.0f) s = (int)ceilf(log2f(rn));
    if (s < 0) s = 0;
    if (s > 30) s = 30;
    const float scale = exp2f((float)(-s));
    #pragma unroll
    for (int j = 0; j < SA; ++j) A[j] *= scale;
    const int smax = max(s, __shfl_xor(s, 32, 64));

    // ---- degree-6 Paterson-Stockmeyer Taylor: 3 matmuls ----
    float A2[SA], A3[SA], T[SA];
    stageRow(stage, A, row, act);
    mmB(A2, A, stage);
    mmB(A3, A2, stage);
    #pragma unroll
    for (int j = 0; j < SA; ++j) {
        float id = (j == row) ? 1.0f : 0.0f;
        T[j] = (1.0f/6.0f)*id + (1.0f/24.0f)*A[j] + (1.0f/120.0f)*A2[j] + (1.0f/720.0f)*A3[j];
    }
    stageRow(stage, T, row, act);      // stage B1
    {
        float P1[SA];
        mmB(P1, A3, stage);
        #pragma unroll
        for (int j = 0; j < SA; ++j) {
            float id = (j == row) ? 1.0f : 0.0f;
            T[j] = P1[j] + id + A[j] + 0.5f * A2[j];
        }
    }
    // ---- squarings (typically 0) ----
    for (int it = 0; it < smax; ++it) {
        stageRow(stage, T, row, act);
        float Tn[SA];
        mmB(Tn, T, stage);
        const bool doit = it < s;
        #pragma unroll
        for (int j = 0; j < SA; ++j) T[j] = doit ? Tn[j] : T[j];
    }
    stageRow(stage, T, row, act);      // final P into wave's slot

    // ---- per-wave gather + stream: out[mb,l,kk,:] = P[kk][seq[l]][:] ----
    // Wave-private LDS: no block barrier. 64 lanes x 80 iters = 5120 float4.
    const float4* pv = reinterpret_cast<const float4*>(sP) + w * (KDIM * SA * SA / 4);
    const int*    sq = sSeq + w * LDIM;
    float4* o4 = reinterpret_cast<float4*>(out) + (size_t)mb * NCH;

    #pragma unroll 4
    for (int f = lane; f < NCH; f += 64) {
        const int l  = (f * 6554) >> 16;   // f/10, exact for f < 16384
        const int ch = f - l * 10;
        const int kk = (ch >= 5) ? 1 : 0;
        const int c4 = ch - kk * 5;
        o4[f] = pv[(kk * SA + sq[l]) * 5 + c4];
    }
}

extern "C" void kernel_launch(void* const* d_in, const int* in_sizes, int n_in,
                              void* d_out, int out_size, void* d_ws, size_t ws_size,
                              hipStream_t stream) {
    const int*   seq  = (const int*)d_in[0];
    const int*   ridx = (const int*)d_in[1];
    const float* tauk = (const float*)d_in[2];
    const float* Ek   = (const float*)d_in[3];
    const float* eqk  = (const float*)d_in[4];
    float* out = (float*)d_out;

    ancprobs_fused_kernel<<<(MDIM * BDIM) / PPB, THREADS, 0, stream>>>(
        seq, ridx, tauk, Ek, eqk, out);
}